// Round 1
// baseline (170.279 us; speedup 1.0000x reference)
//
#include <hip/hip_runtime.h>
#include <cstdint>

#define MDIM 2048
#define KDIM 1024
#define CDIM 8192
#define BM 128
#define BN 128
#define BK 32
#define NCHUNK (2 * (CDIM / BN))   // 128 partial chunks of 64 cols each

typedef __attribute__((ext_vector_type(8))) __bf16 bf16x8;
typedef __attribute__((ext_vector_type(4))) float f32x4;

// ---------- helpers ----------
__device__ __forceinline__ unsigned short f2bf(float f) {
  unsigned u = __float_as_uint(f);
  u += 0x7fffu + ((u >> 16) & 1u);   // RNE
  return (unsigned short)(u >> 16);
}

__device__ __forceinline__ void async_ld16(const void* g, void* l) {
  __builtin_amdgcn_global_load_lds(
      (__attribute__((address_space(1))) void*)(g),
      (__attribute__((address_space(3))) void*)(l),
      16, 0, 0);
}

// ---------- K0a: convert x to bf16 ----------
__global__ __launch_bounds__(256) void convert_x(const float* __restrict__ x,
                                                 unsigned short* __restrict__ xb) {
  const int row = blockIdx.x, t = threadIdx.x;
  const float4 v = ((const float4*)(x + (size_t)row * KDIM))[t];
  ushort4 o;
  o.x = f2bf(v.x); o.y = f2bf(v.y); o.z = f2bf(v.z); o.w = f2bf(v.w);
  ((ushort4*)(xb + (size_t)row * KDIM))[t] = o;
}

// ---------- K0b: convert centroids to bf16 + c2 = ||c||^2 (fp32) ----------
__global__ __launch_bounds__(256) void convert_c(const float* __restrict__ c,
                                                 unsigned short* __restrict__ cb,
                                                 float* __restrict__ c2) {
  const int row = blockIdx.x, t = threadIdx.x;
  const float4 v = ((const float4*)(c + (size_t)row * KDIM))[t];
  ushort4 o;
  o.x = f2bf(v.x); o.y = f2bf(v.y); o.z = f2bf(v.z); o.w = f2bf(v.w);
  ((ushort4*)(cb + (size_t)row * KDIM))[t] = o;
  float p = v.x * v.x + v.y * v.y + v.z * v.z + v.w * v.w;
  for (int d = 32; d; d >>= 1) p += __shfl_down(p, d, 64);
  __shared__ float red[4];
  if ((t & 63) == 0) red[t >> 6] = p;
  __syncthreads();
  if (t == 0) c2[row] = red[0] + red[1] + red[2] + red[3];
}

// ---------- K1: bf16 MFMA GEMM (s = 2*x.c - c2) + fused per-64col online softmax/argmax ----------
__global__ __launch_bounds__(256) void gemm_reduce(
    const unsigned short* __restrict__ Ab, const unsigned short* __restrict__ Bb,
    const float* __restrict__ c2,
    float* __restrict__ pm, float* __restrict__ pl, int* __restrict__ pidx) {
  __shared__ __align__(16) unsigned short As[BM * BK];
  __shared__ __align__(16) unsigned short Bs[BN * BK];
  const int tid = threadIdx.x;
  const int wave = tid >> 6, lane = tid & 63;
  const int wm = wave >> 1, wn = wave & 1;
  const int bn = blockIdx.x, bm = blockIdx.y;
  const int quad = lane >> 4, c16 = lane & 15;

  f32x4 acc[4][4] = {};

  // staging: each wave stages 32 rows of A-tile and 32 rows of B-tile,
  // 16B per lane: row = base + lane/4, kofs = (lane&3)*8
  const int srow = lane >> 2;
  const int scol = (lane & 3) * 8;
  const unsigned short* ag = Ab + (size_t)(bm * BM + wave * 32 + srow) * KDIM + scol;
  const unsigned short* bg = Bb + (size_t)(bn * BN + wave * 32 + srow) * KDIM + scol;
  unsigned short* asl = &As[(wave * 32) * BK];   // wave-uniform LDS base
  unsigned short* bsl = &Bs[(wave * 32) * BK];

  for (int k0 = 0; k0 < KDIM; k0 += BK) {
    async_ld16(ag + k0, asl);
    async_ld16(ag + k0 + 16 * KDIM, asl + 16 * BK);
    async_ld16(bg + k0, bsl);
    async_ld16(bg + k0 + 16 * KDIM, bsl + 16 * BK);
    __syncthreads();   // drains vmcnt -> LDS valid
    bf16x8 a[4], b[4];
#pragma unroll
    for (int mt = 0; mt < 4; ++mt)
      a[mt] = *(const bf16x8*)&As[(wm * 64 + mt * 16 + c16) * BK + quad * 8];
#pragma unroll
    for (int nt = 0; nt < 4; ++nt)
      b[nt] = *(const bf16x8*)&Bs[(wn * 64 + nt * 16 + c16) * BK + quad * 8];
#pragma unroll
    for (int mt = 0; mt < 4; ++mt)
#pragma unroll
      for (int nt = 0; nt < 4; ++nt)
        acc[mt][nt] = __builtin_amdgcn_mfma_f32_16x16x32_bf16(a[mt], b[nt], acc[mt][nt], 0, 0, 0);
    __syncthreads();
  }

  // Epilogue: C/D layout: col = lane&15, row = quad*4 + reg.
  // Each wave owns a 64x64 subtile: rows wm*64.., cols wn*64..
  const int colbase = bn * BN + wn * 64;
  float c2v[4];
#pragma unroll
  for (int nt = 0; nt < 4; ++nt) c2v[nt] = c2[colbase + nt * 16 + c16];

  const int chunk = bn * 2 + wn;
#pragma unroll
  for (int mt = 0; mt < 4; ++mt) {
#pragma unroll
    for (int r = 0; r < 4; ++r) {
      float sv[4];
#pragma unroll
      for (int nt = 0; nt < 4; ++nt) sv[nt] = 2.0f * acc[mt][nt][r] - c2v[nt];
      float m = sv[0];
      int idx = colbase + c16;
#pragma unroll
      for (int nt = 1; nt < 4; ++nt) {
        if (sv[nt] > m) { m = sv[nt]; idx = colbase + nt * 16 + c16; }
      }
      float l = 0.f;
#pragma unroll
      for (int nt = 0; nt < 4; ++nt) l += __expf(sv[nt] - m);
      // butterfly across the 16 lanes sharing this row (low 4 lane bits)
      for (int d = 1; d < 16; d <<= 1) {
        float om = __shfl_xor(m, d, 64);
        float ol = __shfl_xor(l, d, 64);
        int oi = __shfl_xor(idx, d, 64);
        float M = fmaxf(m, om);
        l = l * __expf(m - M) + ol * __expf(om - M);
        idx = (om > m || (om == m && oi < idx)) ? oi : idx;
        m = M;
      }
      if (c16 == 0) {
        const int row = bm * BM + wm * 64 + mt * 16 + quad * 4 + r;
        pm[(size_t)chunk * MDIM + row] = m;
        pl[(size_t)chunk * MDIM + row] = l;
        pidx[(size_t)chunk * MDIM + row] = idx;
      }
    }
  }
}

// ---------- K2: sy[b] = 2 * x_b . cent_{y_b} - c2[y_b]  (fp32) ----------
__global__ __launch_bounds__(256) void sy_kernel(const float* __restrict__ x,
                                                 const int* __restrict__ y,
                                                 const float* __restrict__ cent,
                                                 const float* __restrict__ c2,
                                                 float* __restrict__ sy) {
  const int row = blockIdx.x, t = threadIdx.x;
  const int yc = y[row];
  const float4 a = ((const float4*)(x + (size_t)row * KDIM))[t];
  const float4 b = ((const float4*)(cent + (size_t)yc * KDIM))[t];
  float p = a.x * b.x + a.y * b.y + a.z * b.z + a.w * b.w;
  for (int d = 32; d; d >>= 1) p += __shfl_down(p, d, 64);
  __shared__ float red[4];
  if ((t & 63) == 0) red[t >> 6] = p;
  __syncthreads();
  if (t == 0) sy[row] = 2.0f * (red[0] + red[1] + red[2] + red[3]) - c2[yc];
}

// ---------- K3: combine 128 chunks per row -> loss_row, correct_row; atomic accum ----------
__global__ __launch_bounds__(256) void combine_kernel(
    const float* __restrict__ pm, const float* __restrict__ pl,
    const int* __restrict__ pidx, const float* __restrict__ sy,
    const int* __restrict__ y, float* __restrict__ accum) {
  const int row = blockIdx.x * blockDim.x + threadIdx.x;
  float M = -3.402823466e38f, L = 0.f;
  int g = 0x7fffffff;
  for (int c = 0; c < NCHUNK; ++c) {
    const float m = pm[(size_t)c * MDIM + row];
    const float l = pl[(size_t)c * MDIM + row];
    const int id = pidx[(size_t)c * MDIM + row];
    const float nM = fmaxf(M, m);
    L = L * __expf(M - nM) + l * __expf(m - nM);
    g = (m > M || (m == M && id < g)) ? id : g;
    M = nM;
  }
  float loss = __logf(L) + M - sy[row];
  float corr = (g == y[row]) ? 1.f : 0.f;
  for (int d = 32; d; d >>= 1) {
    loss += __shfl_down(loss, d, 64);
    corr += __shfl_down(corr, d, 64);
  }
  __shared__ float rl[4], rc[4];
  const int t = threadIdx.x;
  if ((t & 63) == 0) { rl[t >> 6] = loss; rc[t >> 6] = corr; }
  __syncthreads();
  if (t == 0) {
    atomicAdd(accum + 0, rl[0] + rl[1] + rl[2] + rl[3]);
    atomicAdd(accum + 1, rc[0] + rc[1] + rc[2] + rc[3]);
  }
}

// ---------- K4: finalize means ----------
__global__ void finalize(const float* __restrict__ accum, float* __restrict__ out) {
  out[0] = accum[0] * (1.0f / MDIM);
  out[1] = accum[1] * (1.0f / MDIM);
}

// ---------- launch ----------
extern "C" void kernel_launch(void* const* d_in, const int* in_sizes, int n_in,
                              void* d_out, int out_size, void* d_ws, size_t ws_size,
                              hipStream_t stream) {
  const float* x = (const float*)d_in[0];
  const int* y = (const int*)d_in[1];
  const float* cent = (const float*)d_in[2];
  float* out = (float*)d_out;

  char* ws = (char*)d_ws;
  const size_t OFF_XB = 0;                                   // 2048*1024*2  = 4 MB
  const size_t OFF_CB = OFF_XB + (size_t)MDIM * KDIM * 2;    // 8192*1024*2  = 16 MB
  const size_t OFF_C2 = OFF_CB + (size_t)CDIM * KDIM * 2;    // 32 KB
  const size_t OFF_SY = OFF_C2 + (size_t)CDIM * 4;           // 8 KB
  const size_t OFF_PM = OFF_SY + (size_t)MDIM * 4;           // 1 MB
  const size_t OFF_PL = OFF_PM + (size_t)NCHUNK * MDIM * 4;  // 1 MB
  const size_t OFF_PI = OFF_PL + (size_t)NCHUNK * MDIM * 4;  // 1 MB
  const size_t OFF_AC = OFF_PI + (size_t)NCHUNK * MDIM * 4;  // 8 B
  const size_t NEED = OFF_AC + 16;
  if (ws_size < NEED) return;  // loud failure rather than corruption

  unsigned short* xb = (unsigned short*)(ws + OFF_XB);
  unsigned short* cb = (unsigned short*)(ws + OFF_CB);
  float* c2 = (float*)(ws + OFF_C2);
  float* sy = (float*)(ws + OFF_SY);
  float* pm = (float*)(ws + OFF_PM);
  float* pl = (float*)(ws + OFF_PL);
  int* pidx = (int*)(ws + OFF_PI);
  float* accum = (float*)(ws + OFF_AC);

  hipMemsetAsync(accum, 0, 2 * sizeof(float), stream);
  convert_x<<<MDIM, 256, 0, stream>>>(x, xb);
  convert_c<<<CDIM, 256, 0, stream>>>(cent, cb, c2);
  gemm_reduce<<<dim3(CDIM / BN, MDIM / BM), 256, 0, stream>>>(xb, cb, c2, pm, pl, pidx);
  sy_kernel<<<MDIM, 256, 0, stream>>>(x, y, cent, c2, sy);
  combine_kernel<<<MDIM / 256, 256, 0, stream>>>(pm, pl, pidx, sy, y, accum);
  finalize<<<1, 1, 0, stream>>>(accum, out);
}

// Round 2
// 153.493 us; speedup vs baseline: 1.1094x; 1.1094x over previous
//
#include <hip/hip_runtime.h>
#include <cstdint>

#define MDIM 2048
#define KDIM 1024
#define CDIM 8192
#define BM 128
#define BN 128
#define BK 32
#define NCHUNK (2 * (CDIM / BN))   // 128 partial chunks of 64 cols each

typedef __attribute__((ext_vector_type(8))) __bf16 bf16x8;
typedef __attribute__((ext_vector_type(4))) float f32x4;

// ---------- helpers ----------
__device__ __forceinline__ unsigned short f2bf(float f) {
  unsigned u = __float_as_uint(f);
  u += 0x7fffu + ((u >> 16) & 1u);   // RNE
  return (unsigned short)(u >> 16);
}

__device__ __forceinline__ void async_ld16(const void* g, void* l) {
  __builtin_amdgcn_global_load_lds(
      (__attribute__((address_space(1))) void*)(g),
      (__attribute__((address_space(3))) void*)(l),
      16, 0, 0);
}

// ---------- K0: fused convert x & centroids to bf16; c2 = ||c||^2 ----------
__global__ __launch_bounds__(256) void convert_all(const float* __restrict__ x,
                                                   const float* __restrict__ cent,
                                                   unsigned short* __restrict__ xb,
                                                   unsigned short* __restrict__ cb,
                                                   float* __restrict__ c2) {
  const int b = blockIdx.x, t = threadIdx.x;
  if (b < MDIM) {
    const float4 v = ((const float4*)(x + (size_t)b * KDIM))[t];
    ushort4 o;
    o.x = f2bf(v.x); o.y = f2bf(v.y); o.z = f2bf(v.z); o.w = f2bf(v.w);
    ((ushort4*)(xb + (size_t)b * KDIM))[t] = o;
  } else {
    const int row = b - MDIM;
    const float4 v = ((const float4*)(cent + (size_t)row * KDIM))[t];
    ushort4 o;
    o.x = f2bf(v.x); o.y = f2bf(v.y); o.z = f2bf(v.z); o.w = f2bf(v.w);
    ((ushort4*)(cb + (size_t)row * KDIM))[t] = o;
    float p = v.x * v.x + v.y * v.y + v.z * v.z + v.w * v.w;
    for (int d = 32; d; d >>= 1) p += __shfl_down(p, d, 64);
    __shared__ float red[4];
    if ((t & 63) == 0) red[t >> 6] = p;
    __syncthreads();
    if (t == 0) c2[row] = red[0] + red[1] + red[2] + red[3];
  }
}

// ---------- K1: bf16 MFMA GEMM (s = 2*x.c - c2) + fused per-64col online softmax/argmax ----------
__global__ __launch_bounds__(256) void gemm_reduce(
    const unsigned short* __restrict__ Ab, const unsigned short* __restrict__ Bb,
    const float* __restrict__ c2,
    float* __restrict__ pm, float* __restrict__ pl, int* __restrict__ pidx) {
  __shared__ __align__(16) unsigned short As[BM * BK];
  __shared__ __align__(16) unsigned short Bs[BN * BK];
  const int tid = threadIdx.x;
  const int wave = tid >> 6, lane = tid & 63;
  const int wm = wave >> 1, wn = wave & 1;
  const int bn = blockIdx.x, bm = blockIdx.y;
  const int quad = lane >> 4, c16 = lane & 15;

  f32x4 acc[4][4] = {};

  const int srow = lane >> 2;
  const int scol = (lane & 3) * 8;
  const unsigned short* ag = Ab + (size_t)(bm * BM + wave * 32 + srow) * KDIM + scol;
  const unsigned short* bg = Bb + (size_t)(bn * BN + wave * 32 + srow) * KDIM + scol;
  unsigned short* asl = &As[(wave * 32) * BK];   // wave-uniform LDS base
  unsigned short* bsl = &Bs[(wave * 32) * BK];

  for (int k0 = 0; k0 < KDIM; k0 += BK) {
    async_ld16(ag + k0, asl);
    async_ld16(ag + k0 + 16 * KDIM, asl + 16 * BK);
    async_ld16(bg + k0, bsl);
    async_ld16(bg + k0 + 16 * KDIM, bsl + 16 * BK);
    __syncthreads();
    bf16x8 a[4], b[4];
#pragma unroll
    for (int mt = 0; mt < 4; ++mt)
      a[mt] = *(const bf16x8*)&As[(wm * 64 + mt * 16 + c16) * BK + quad * 8];
#pragma unroll
    for (int nt = 0; nt < 4; ++nt)
      b[nt] = *(const bf16x8*)&Bs[(wn * 64 + nt * 16 + c16) * BK + quad * 8];
#pragma unroll
    for (int mt = 0; mt < 4; ++mt)
#pragma unroll
      for (int nt = 0; nt < 4; ++nt)
        acc[mt][nt] = __builtin_amdgcn_mfma_f32_16x16x32_bf16(a[mt], b[nt], acc[mt][nt], 0, 0, 0);
    __syncthreads();
  }

  // Epilogue: C/D layout: col = lane&15, row = quad*4 + reg.
  const int colbase = bn * BN + wn * 64;
  float c2v[4];
#pragma unroll
  for (int nt = 0; nt < 4; ++nt) c2v[nt] = c2[colbase + nt * 16 + c16];

  const int chunk = bn * 2 + wn;
#pragma unroll
  for (int mt = 0; mt < 4; ++mt) {
#pragma unroll
    for (int r = 0; r < 4; ++r) {
      float sv[4];
#pragma unroll
      for (int nt = 0; nt < 4; ++nt) sv[nt] = 2.0f * acc[mt][nt][r] - c2v[nt];
      float m = sv[0];
      int idx = colbase + c16;
#pragma unroll
      for (int nt = 1; nt < 4; ++nt) {
        if (sv[nt] > m) { m = sv[nt]; idx = colbase + nt * 16 + c16; }
      }
      float l = 0.f;
#pragma unroll
      for (int nt = 0; nt < 4; ++nt) l += __expf(sv[nt] - m);
      for (int d = 1; d < 16; d <<= 1) {
        float om = __shfl_xor(m, d, 64);
        float ol = __shfl_xor(l, d, 64);
        int oi = __shfl_xor(idx, d, 64);
        float M = fmaxf(m, om);
        l = l * __expf(m - M) + ol * __expf(om - M);
        idx = (om > m || (om == m && oi < idx)) ? oi : idx;
        m = M;
      }
      if (c16 == 0) {
        const int row = bm * BM + wm * 64 + mt * 16 + quad * 4 + r;
        // row-major [row][chunk] so combine reads coalesce
        pm[(size_t)row * NCHUNK + chunk] = m;
        pl[(size_t)row * NCHUNK + chunk] = l;
        pidx[(size_t)row * NCHUNK + chunk] = idx;
      }
    }
  }
}

// ---------- K2: per-row combine (128 threads = 128 chunks) + fused sy dot ----------
__global__ __launch_bounds__(128) void combine_kernel(
    const float* __restrict__ pm, const float* __restrict__ pl,
    const int* __restrict__ pidx, const float* __restrict__ x,
    const float* __restrict__ cent, const float* __restrict__ c2,
    const int* __restrict__ y,
    float* __restrict__ loss_part, float* __restrict__ corr_part) {
  const int row = blockIdx.x, t = threadIdx.x;  // t = chunk id, 0..127
  const int yc = y[row];

  float m = pm[(size_t)row * NCHUNK + t];
  float l = pl[(size_t)row * NCHUNK + t];
  int idx = pidx[(size_t)row * NCHUNK + t];

  // fp32 partial dot: 8 elements per thread
  const float4* xa = (const float4*)(x + (size_t)row * KDIM) + t * 2;
  const float4* ca = (const float4*)(cent + (size_t)yc * KDIM) + t * 2;
  const float4 a0 = xa[0], a1 = xa[1], b0 = ca[0], b1 = ca[1];
  float dot = a0.x * b0.x + a0.y * b0.y + a0.z * b0.z + a0.w * b0.w
            + a1.x * b1.x + a1.y * b1.y + a1.z * b1.z + a1.w * b1.w;

  // butterfly within each wave
  for (int d = 1; d < 64; d <<= 1) {
    const float om = __shfl_xor(m, d, 64);
    const float ol = __shfl_xor(l, d, 64);
    const int oi = __shfl_xor(idx, d, 64);
    const float od = __shfl_xor(dot, d, 64);
    const float M = fmaxf(m, om);
    l = l * __expf(m - M) + ol * __expf(om - M);
    idx = (om > m || (om == m && oi < idx)) ? oi : idx;
    m = M;
    dot += od;
  }
  __shared__ float sm[2], sl[2], sd[2];
  __shared__ int si[2];
  if ((t & 63) == 0) { sm[t >> 6] = m; sl[t >> 6] = l; si[t >> 6] = idx; sd[t >> 6] = dot; }
  __syncthreads();
  if (t == 0) {
    const float m0 = sm[0], m1 = sm[1];
    const float M = fmaxf(m0, m1);
    const float L = sl[0] * __expf(m0 - M) + sl[1] * __expf(m1 - M);
    int g;
    if (m1 > m0 || (m1 == m0 && si[1] < si[0])) g = si[1]; else g = si[0];
    const float sy = 2.0f * (sd[0] + sd[1]) - c2[yc];
    loss_part[row] = __logf(L) + M - sy;
    corr_part[row] = (g == yc) ? 1.f : 0.f;
  }
}

// ---------- K3: finalize means ----------
__global__ __launch_bounds__(256) void finalize(const float* __restrict__ loss_part,
                                                const float* __restrict__ corr_part,
                                                float* __restrict__ out) {
  const int t = threadIdx.x;
  float s0 = 0.f, s1 = 0.f;
  for (int i = t; i < MDIM; i += 256) { s0 += loss_part[i]; s1 += corr_part[i]; }
  for (int d = 32; d; d >>= 1) {
    s0 += __shfl_down(s0, d, 64);
    s1 += __shfl_down(s1, d, 64);
  }
  __shared__ float r0[4], r1[4];
  if ((t & 63) == 0) { r0[t >> 6] = s0; r1[t >> 6] = s1; }
  __syncthreads();
  if (t == 0) {
    out[0] = (r0[0] + r0[1] + r0[2] + r0[3]) * (1.0f / MDIM);
    out[1] = (r1[0] + r1[1] + r1[2] + r1[3]) * (1.0f / MDIM);
  }
}

// ---------- launch ----------
extern "C" void kernel_launch(void* const* d_in, const int* in_sizes, int n_in,
                              void* d_out, int out_size, void* d_ws, size_t ws_size,
                              hipStream_t stream) {
  const float* x = (const float*)d_in[0];
  const int* y = (const int*)d_in[1];
  const float* cent = (const float*)d_in[2];
  float* out = (float*)d_out;

  char* ws = (char*)d_ws;
  const size_t OFF_XB = 0;                                   // 4 MB
  const size_t OFF_CB = OFF_XB + (size_t)MDIM * KDIM * 2;    // 16 MB
  const size_t OFF_C2 = OFF_CB + (size_t)CDIM * KDIM * 2;    // 32 KB
  const size_t OFF_PM = OFF_C2 + (size_t)CDIM * 4;           // 1 MB
  const size_t OFF_PL = OFF_PM + (size_t)NCHUNK * MDIM * 4;  // 1 MB
  const size_t OFF_PI = OFF_PL + (size_t)NCHUNK * MDIM * 4;  // 1 MB
  const size_t OFF_LP = OFF_PI + (size_t)NCHUNK * MDIM * 4;  // 8 KB
  const size_t OFF_CP = OFF_LP + (size_t)MDIM * 4;           // 8 KB
  const size_t NEED = OFF_CP + (size_t)MDIM * 4;
  if (ws_size < NEED) return;

  unsigned short* xb = (unsigned short*)(ws + OFF_XB);
  unsigned short* cb = (unsigned short*)(ws + OFF_CB);
  float* c2 = (float*)(ws + OFF_C2);
  float* pm = (float*)(ws + OFF_PM);
  float* pl = (float*)(ws + OFF_PL);
  int* pidx = (int*)(ws + OFF_PI);
  float* loss_part = (float*)(ws + OFF_LP);
  float* corr_part = (float*)(ws + OFF_CP);

  convert_all<<<MDIM + CDIM, 256, 0, stream>>>(x, cent, xb, cb, c2);
  gemm_reduce<<<dim3(CDIM / BN, MDIM / BM), 256, 0, stream>>>(xb, cb, c2, pm, pl, pidx);
  combine_kernel<<<MDIM, 128, 0, stream>>>(pm, pl, pidx, x, cent, c2, y, loss_part, corr_part);
  finalize<<<1, 256, 0, stream>>>(loss_part, corr_part, out);
}